// Round 21
// baseline (172.116 us; speedup 1.0000x reference)
//
#include <hip/hip_runtime.h>
#include <hip/hip_bf16.h>

typedef __bf16 bf16_t;
typedef __bf16 bf16x8 __attribute__((ext_vector_type(8)));
typedef __bf16 bf16x4 __attribute__((ext_vector_type(4)));
typedef float f32x4 __attribute__((ext_vector_type(4)));

#define D_MODEL 1024
#define HEADS 16
#define D_K 64
#define SEQ 2048
#define BATCH 2
#define MTOT (SEQ * BATCH) /* 4096 */
#define LOG2E 1.4426950408889634f
#define QSCALE (0.125f * LOG2E) /* fold softmax scale AND log2e into Q */

// async global->LDS, 16B per lane; LDS dest = wave-uniform base + lane*16
#define GLDS16(g, l)                                                        \
  __builtin_amdgcn_global_load_lds(                                        \
      (const __attribute__((address_space(1))) unsigned int*)(g),          \
      (__attribute__((address_space(3))) unsigned int*)(l), 16, 0, 0)

// ------------------------------------------------------------------
// fp32 -> bf16 convert, ALL 7 arrays in ONE launch (R18, verified).
// ------------------------------------------------------------------
__global__ __launch_bounds__(256) void cvt_all(const float* q, const float* k,
                                               const float* v, const float* wq,
                                               const float* wk, const float* wv,
                                               const float* wo, bf16_t* xq, bf16_t* xk,
                                               bf16_t* xv, bf16_t* wqkv, bf16_t* wob) {
  const size_t nIn = (size_t)MTOT * D_MODEL;   // 2^22
  const size_t nW = (size_t)D_MODEL * D_MODEL; // 2^20
  size_t e = ((size_t)blockIdx.x * 256 + threadIdx.x) * 8;
  const float* s;
  bf16_t* d;
  size_t off;
  if (e < 3 * nIn) {
    int j = (int)(e >> 22);
    off = e & (nIn - 1);
    s = j == 0 ? q : (j == 1 ? k : v);
    d = j == 0 ? xq : (j == 1 ? xk : xv);
  } else {
    size_t e2 = e - 3 * nIn;
    int j = (int)(e2 >> 20);
    off = e2 & (nW - 1);
    s = j == 0 ? wq : (j == 1 ? wk : (j == 2 ? wv : wo));
    d = j == 3 ? wob : (wqkv + (size_t)j * nW);
  }
  float4 a = *(const float4*)(s + off);
  float4 b = *(const float4*)(s + off + 4);
  bf16x8 o;
  o[0] = (bf16_t)a.x; o[1] = (bf16_t)a.y; o[2] = (bf16_t)a.z; o[3] = (bf16_t)a.w;
  o[4] = (bf16_t)b.x; o[5] = (bf16_t)b.y; o[6] = (bf16_t)b.z; o[7] = (bf16_t)b.w;
  *(bf16x8*)(d + off) = o;
}

// ------------------------------------------------------------------
// Fused QKV projection GEMM — R12-EXACT champion (63.4 us measured).
// ------------------------------------------------------------------
__global__ __launch_bounds__(512, 2) void gemm_qkv(const bf16_t* __restrict__ Xq,
                                                   const bf16_t* __restrict__ Xk,
                                                   const bf16_t* __restrict__ Xv,
                                                   const bf16_t* __restrict__ Wqkv,
                                                   const float* __restrict__ bq,
                                                   const float* __restrict__ bk,
                                                   const float* __restrict__ bv,
                                                   bf16_t* __restrict__ qa,
                                                   bf16_t* __restrict__ ka,
                                                   bf16_t* __restrict__ vt) {
  __shared__ __align__(16) bf16_t As[3][128 * 64];  // 16 KB x3
  __shared__ __align__(16) bf16_t Bs[3][128 * 64];  // 16 KB x3
  const int t = threadIdx.x;
  const int f = blockIdx.x;
  const int xcd = f & 7, fi = f >> 3;  // fi 0..95
  const int by = xcd * 4 + (fi & 3);   // row-panel 0..31 (XCD-clustered)
  const int col = fi >> 2;             // col-panel 0..23
  const int seg = col >> 3;            // 0=Q 1=K 2=V
  const bf16_t* X = seg == 0 ? Xq : (seg == 1 ? Xk : Xv);
  const float* bias = seg == 0 ? bq : (seg == 1 ? bk : bv);
  const float scale = seg == 0 ? QSCALE : 1.0f;
  const int m0 = by * 128;
  const int n0g = col * 128;  // global col in [0,3072)
  const int w = t >> 6, l = t & 63, lr = l & 15, lg = l >> 4;
  const int wm = (w >> 2) * 64, wn = (w & 3) * 32;

  f32x4 acc[4][2] = {};

  const int srow0 = t >> 3;
  const int sck = (((t & 7) ^ (srow0 & 7)) << 3);
  const int sx = (lr & 7) << 4;  // read-side XOR (row&7 == lr&7)

#define QKV_STAGE(buf, kt)                                                      \
  {                                                                             \
    _Pragma("unroll") for (int p = 0; p < 2; ++p) {                             \
      int row = (p * 512 + t) >> 3;                                             \
      int wb = (p * 512 + w * 64) * 8;                                          \
      GLDS16(&X[(size_t)(m0 + row) * D_MODEL + (kt) + sck], As[buf] + wb);      \
      GLDS16(&Wqkv[(size_t)(n0g + row) * D_MODEL + (kt) + sck], Bs[buf] + wb);  \
    }                                                                           \
  }

  QKV_STAGE(0, 0);
  QKV_STAGE(1, 64);

  int cur = 0;
  for (int step = 0; step < 16; ++step) {
    if (step < 15)
      asm volatile("s_waitcnt vmcnt(4)" ::: "memory");
    else
      asm volatile("s_waitcnt vmcnt(0)" ::: "memory");
    __builtin_amdgcn_s_barrier();  // raw: no vmcnt(0) drain
    if (step + 2 < 16) {
      int nb = cur + 2; nb = nb >= 3 ? nb - 3 : nb;
      QKV_STAGE(nb, (step + 2) * 64);  // overwrites buf (step-1)%3: safe
    }
#pragma unroll
    for (int kk = 0; kk < 2; ++kk) {
      bf16x8 a[4], b[2];
#pragma unroll
      for (int i = 0; i < 4; ++i)
        a[i] = *(const bf16x8*)((const char*)As[cur] + (wm + i * 16 + lr) * 128 +
                                ((kk * 64 + lg * 16) ^ sx));
#pragma unroll
      for (int j = 0; j < 2; ++j)
        b[j] = *(const bf16x8*)((const char*)Bs[cur] + (wn + j * 16 + lr) * 128 +
                                ((kk * 64 + lg * 16) ^ sx));
      __builtin_amdgcn_s_setprio(1);
#pragma unroll
      for (int i = 0; i < 4; ++i)
#pragma unroll
        for (int j = 0; j < 2; ++j)
          acc[i][j] = __builtin_amdgcn_mfma_f32_16x16x32_bf16(a[i], b[j], acc[i][j], 0, 0, 0);
      __builtin_amdgcn_s_setprio(0);
    }
    cur = cur + 1 >= 3 ? 0 : cur + 1;
  }
#undef QKV_STAGE

#pragma unroll
  for (int i = 0; i < 4; ++i) {
#pragma unroll
    for (int j = 0; j < 2; ++j) {
      int lc = ((n0g + wn) & 1023) + j * 16 + lr;  // segment-local col
      float bb = bias[lc];
      int h = lc >> 6, d = lc & 63;
#pragma unroll
      for (int ii = 0; ii < 4; ++ii) {
        int row = m0 + wm + i * 16 + lg * 4 + ii;
        float v = (acc[i][j][ii] + bb) * scale;
        int s = row >> 1, b2 = row & 1;
        if (seg == 2)
          vt[(((size_t)(b2 * HEADS + h) * D_K) + d) * SEQ + s] = (bf16_t)v;
        else if (seg == 1)
          ka[(((size_t)(b2 * HEADS + h) * SEQ) + s) * D_K + d] = (bf16_t)v;
        else
          qa[(((size_t)(b2 * HEADS + h) * SEQ) + s) * D_K + d] = (bf16_t)v;
      }
    }
  }
}

// ------------------------------------------------------------------
// Output GEMM (R12 version, verified).
// ------------------------------------------------------------------
__global__ __launch_bounds__(512) void gemm_out(const bf16_t* __restrict__ X,
                                                const bf16_t* __restrict__ W,
                                                const float* __restrict__ bias,
                                                float* __restrict__ out) {
  __shared__ __align__(16) bf16_t As[2][128 * 64];
  __shared__ __align__(16) bf16_t Bs[2][128 * 64];
  const int t = threadIdx.x;
  const int f = blockIdx.x;
  const int xcd = f & 7, fi = f >> 3;
  const int by = xcd * 4 + (fi & 3);
  const int bx = fi >> 2;  // 0..7
  const int m0 = by * 128, n0 = bx * 128;
  const int w = t >> 6, l = t & 63, lr = l & 15, lg = l >> 4;
  const int wm = (w >> 2) * 64, wn = (w & 3) * 32;
  const int srow0 = t >> 3;
  const int sck = (((t & 7) ^ (srow0 & 7)) << 3);
  const int sx = (lr & 7) << 4;

  f32x4 acc[4][2] = {};

#define OUT_STAGE(buf, kt)                                                      \
  {                                                                             \
    _Pragma("unroll") for (int p = 0; p < 2; ++p) {                             \
      int row = (p * 512 + t) >> 3;                                             \
      int wb = (p * 512 + w * 64) * 8;                                          \
      GLDS16(&X[(size_t)(m0 + row) * D_MODEL + (kt) + sck], As[buf] + wb);      \
      GLDS16(&W[(size_t)(n0 + row) * D_MODEL + (kt) + sck], Bs[buf] + wb);      \
    }                                                                           \
  }

  OUT_STAGE(0, 0);
  __syncthreads();

  for (int step = 0; step < 16; ++step) {
    const int cur = step & 1;
    if (step + 1 < 16) OUT_STAGE(cur ^ 1, (step + 1) * 64);
#pragma unroll
    for (int kk = 0; kk < 2; ++kk) {
      bf16x8 a[4], b[2];
#pragma unroll
      for (int i = 0; i < 4; ++i)
        a[i] = *(const bf16x8*)((const char*)As[cur] + (wm + i * 16 + lr) * 128 +
                                ((kk * 64 + lg * 16) ^ sx));
#pragma unroll
      for (int j = 0; j < 2; ++j)
        b[j] = *(const bf16x8*)((const char*)Bs[cur] + (wn + j * 16 + lr) * 128 +
                                ((kk * 64 + lg * 16) ^ sx));
#pragma unroll
      for (int i = 0; i < 4; ++i)
#pragma unroll
        for (int j = 0; j < 2; ++j)
          acc[i][j] = __builtin_amdgcn_mfma_f32_16x16x32_bf16(a[i], b[j], acc[i][j], 0, 0, 0);
    }
    __syncthreads();
  }
#undef OUT_STAGE

#pragma unroll
  for (int i = 0; i < 4; ++i) {
#pragma unroll
    for (int j = 0; j < 2; ++j) {
      int col = n0 + wn + j * 16 + lr;
      float bb = bias[col];
#pragma unroll
      for (int ii = 0; ii < 4; ++ii) {
        int row = m0 + wm + i * 16 + lg * 4 + ii;
        out[(size_t)row * D_MODEL + col] = acc[i][j][ii] + bb;
      }
    }
  }
}

// ------------------------------------------------------------------
// Flash attention, transposed-score form, LDS-staged K/V, NO-MAX softmax
// in exp2 domain — LDS-DIET variant for 3 blocks/CU (24 waves/CU):
//   rbl stored bf16 (4.35KB, bias rel err <0.4%, 3x absmax headroom);
//   P buffer LDP=64 with both-sides XOR swizzle ((lr&7)<<4; writer and
//   reader use the same row lr -> same key; alignment preserved).
// Total LDS 53.5KB (was 59.9) -> 3 blocks/CU, +50% waves for the
// latency-bound phases (MfmaUtil 23 / VALU 24 / HBM 4%).
// 512 threads = 8 waves, 128 q/block, K-tiles of 64, dbuf global_load_lds.
// ------------------------------------------------------------------
#define QBLK 128
#define KVBLK 64
#define NT (SEQ / KVBLK)
#define TBL_N 2175

__global__ __launch_bounds__(512, 4) void attn_kernel(const bf16_t* __restrict__ Qa,
                                                      const bf16_t* __restrict__ Ka,
                                                      const bf16_t* __restrict__ Vt,
                                                      const float* __restrict__ rel,
                                                      bf16_t* __restrict__ ctx) {
  __shared__ bf16_t rbl[TBL_N + 1];                    // reversed, pre-scaled bias (bf16)
  __shared__ __align__(16) bf16_t ks[2][KVBLK * 64];   // [k][d], chunk-swizzled
  __shared__ __align__(16) bf16_t vs[2][KVBLK * 64];   // [d][k], chunk-swizzled
  __shared__ __align__(16) bf16_t p_lds[8][16 * 64];   // per-wave P [q16][k64], XOR-swz

  // bijective XCD swizzle: 512 blocks -> 64 consecutive per XCD (bh-major)
  const int f = blockIdx.x;
  const int nf = (f & 7) * 64 + (f >> 3);
  const int qb = nf & 15, bh = nf >> 4;
  const int h = bh & (HEADS - 1), b2 = bh >> 4;
  const int qbase = qb * QBLK;
  const int t = threadIdx.x, w = t >> 6, l = t & 63, lr = l & 15, lg = l >> 4;

  const bf16_t* Qbh = Qa + (size_t)bh * SEQ * D_K;
  const bf16_t* Kbh = Ka + (size_t)bh * SEQ * D_K;
  const bf16_t* Vbh = Vt + (size_t)bh * D_K * SEQ;

  // reversed bias table: rbl[j] = bf16(log2e * rel_head[qbase + 2174 - j])
  for (int j = t; j < TBL_N; j += 512)
    rbl[j] = (bf16_t)(LOG2E * rel[(size_t)(qbase + (TBL_N - 1) - j) * HEADS + h]);

  // staging: thread t -> 16B chunk (row=t>>3, physchunk=t&7);
  // phys chunk holds source col16 = (t&7) ^ (row&7)  (read-side XOR matches)
  const int srow = t >> 3;
  const int scol = (((t & 7) ^ (srow & 7)) << 3);
  const int sldsoff = w * 512;

  const int qloc = w * 16 + lr;  // this lane's q (block-local)
  bf16x8 qf[2];
#pragma unroll
  for (int kk = 0; kk < 2; ++kk)
    qf[kk] = *(const bf16x8*)(&Qbh[(size_t)(qbase + qloc) * D_K + kk * 32 + lg * 8]);

  bf16x8 ones;
#pragma unroll
  for (int e = 0; e < 8; ++e) ones[e] = (bf16_t)1.0f;

  GLDS16(Kbh + (size_t)srow * D_K + scol, ks[0] + sldsoff);
  GLDS16(Vbh + (size_t)srow * SEQ + scol, vs[0] + sldsoff);
  __syncthreads();  // drains staging vmcnt + covers rbl

  f32x4 acc_o[4] = {};  // acc_o[c][ii] = O[d = c*16 + lg*4 + ii][q = qloc]
  f32x4 l_acc = {};     // all entries = running denominator for q = qloc
  char* pw = (char*)p_lds[w];
  const int sw = (lr & 7) << 4;          // XOR key: K/V chunks AND P buffer
  const int roff = 127 - qloc + lg * 4;  // reversed-table base offset

  for (int it = 0; it < NT; ++it) {
    const int cur = it & 1;
    const int kt = it * KVBLK;
    if (it + 1 < NT) {
      const int ktn = kt + KVBLK;
      GLDS16(Kbh + (size_t)(ktn + srow) * D_K + scol, ks[cur ^ 1] + sldsoff);
      GLDS16(Vbh + (size_t)srow * SEQ + ktn + scol, vs[cur ^ 1] + sldsoff);
    }
    const char* Kc = (const char*)ks[cur];
    const char* Vc = (const char*)vs[cur];

    // ---- S^T tile in exp2 domain, bias as C-init; P = exp2(z) ----
#pragma unroll
    for (int c = 0; c < 4; ++c) {
      const int r0 = roff + kt + c * 16;
      f32x4 z;
      z[0] = (float)rbl[r0];     z[1] = (float)rbl[r0 + 1];
      z[2] = (float)rbl[r0 + 2]; z[3] = (float)rbl[r0 + 3];
#pragma unroll
      for (int kk = 0; kk < 2; ++kk) {
        bf16x8 kf = *(const bf16x8*)(Kc + (c * 16 + lr) * 128 + ((kk * 64 + lg * 16) ^ sw));
        z = __builtin_amdgcn_mfma_f32_16x16x32_bf16(kf, qf[kk], z, 0, 0, 0);
      }
      bf16x4 pv;
#pragma unroll
      for (int i = 0; i < 4; ++i) pv[i] = (bf16_t)__builtin_amdgcn_exp2f(z[i]);
      *(bf16x4*)(pw + lr * 128 + ((c * 32 + lg * 8) ^ sw)) = pv;
    }

    // ---- PV: O^T += V^T_frag x P_frag ; l += ones x P_frag ----
    __builtin_amdgcn_s_setprio(1);
#pragma unroll
    for (int kk = 0; kk < 2; ++kk) {
      bf16x8 pa = *(const bf16x8*)(pw + lr * 128 + ((kk * 64 + lg * 16) ^ sw));
      l_acc = __builtin_amdgcn_mfma_f32_16x16x32_bf16(ones, pa, l_acc, 0, 0, 0);
#pragma unroll
      for (int c = 0; c < 4; ++c) {
        bf16x8 vf = *(const bf16x8*)(Vc + (c * 16 + lr) * 128 + ((kk * 64 + lg * 16) ^ sw));
        acc_o[c] = __builtin_amdgcn_mfma_f32_16x16x32_bf16(vf, pa, acc_o[c], 0, 0, 0);
      }
    }
    __builtin_amdgcn_s_setprio(0);
    __syncthreads();  // stage(it+1) landed; all waves done reading cur
  }

  const float inv = 1.0f / l_acc[0];

  int qg = qbase + qloc;
  size_t base = ((size_t)qg * BATCH + b2) * D_MODEL + h * D_K;
#pragma unroll
  for (int c = 0; c < 4; ++c) {
    bf16x4 ov;
#pragma unroll
    for (int ii = 0; ii < 4; ++ii) ov[ii] = (bf16_t)(acc_o[c][ii] * inv);
    *(bf16x4*)(&ctx[base + c * 16 + lg * 4]) = ov;
  }
}

// ------------------------------------------------------------------
extern "C" void kernel_launch(void* const* d_in, const int* in_sizes, int n_in,
                              void* d_out, int out_size, void* d_ws, size_t ws_size,
                              hipStream_t stream) {
  const float* query = (const float*)d_in[0];
  const float* key_i = (const float*)d_in[1];
  const float* value = (const float*)d_in[2];
  const float* Wq = (const float*)d_in[3];
  const float* bq = (const float*)d_in[4];
  const float* Wk = (const float*)d_in[5];
  const float* bk = (const float*)d_in[6];
  const float* Wv = (const float*)d_in[7];
  const float* bv = (const float*)d_in[8];
  const float* Wo = (const float*)d_in[9];
  const float* bo = (const float*)d_in[10];
  const float* rel = (const float*)d_in[11];
  float* out = (float*)d_out;

  char* ws = (char*)d_ws;
  size_t off = 0;
  auto alloc = [&](size_t bytes) {
    char* p = ws + off;
    off = (off + bytes + 255) & ~(size_t)255;
    return p;
  };
  const size_t nIn = (size_t)MTOT * D_MODEL;
  const size_t nW = (size_t)D_MODEL * D_MODEL;

  bf16_t* Xq = (bf16_t*)alloc(nIn * 2);
  bf16_t* Xk = (bf16_t*)alloc(nIn * 2);
  bf16_t* Xv = (bf16_t*)alloc(nIn * 2);
  bf16_t* Wqkv = (bf16_t*)alloc(3 * nW * 2);  // Wq | Wk | Wv rows, contiguous
  bf16_t* Wob = (bf16_t*)alloc(nW * 2);
  bf16_t* qa = (bf16_t*)alloc(nIn * 2);   // [B,H,S,64]
  bf16_t* ka = (bf16_t*)alloc(nIn * 2);   // [B,H,S,64]
  bf16_t* vt = (bf16_t*)alloc(nIn * 2);   // [B,H,64,S]
  bf16_t* ctx = (bf16_t*)alloc(nIn * 2);  // [M,1024]

  // one fused cvt launch: (3*nIn + 4*nW)/8 threads = 8192 blocks
  cvt_all<<<dim3(8192), 256, 0, stream>>>(query, key_i, value, Wq, Wk, Wv, Wo, Xq, Xk,
                                          Xv, Wqkv, Wob);

  gemm_qkv<<<dim3(768), 512, 0, stream>>>(Xq, Xk, Xv, Wqkv, bq, bk, bv, qa, ka, vt);

  attn_kernel<<<dim3(512), 512, 0, stream>>>(qa, ka, vt, rel, ctx);

  gemm_out<<<dim3(256), 512, 0, stream>>>(ctx, Wob, bo, out);
}

// Round 22
// 130.551 us; speedup vs baseline: 1.3184x; 1.3184x over previous
//
#include <hip/hip_runtime.h>
#include <hip/hip_bf16.h>

typedef __bf16 bf16_t;
typedef __bf16 bf16x8 __attribute__((ext_vector_type(8)));
typedef __bf16 bf16x4 __attribute__((ext_vector_type(4)));
typedef float f32x4 __attribute__((ext_vector_type(4)));

#define D_MODEL 1024
#define HEADS 16
#define D_K 64
#define SEQ 2048
#define BATCH 2
#define MTOT (SEQ * BATCH) /* 4096 */
#define LOG2E 1.4426950408889634f
#define QSCALE (0.125f * LOG2E) /* fold softmax scale AND log2e into Q */

// async global->LDS, 16B per lane; LDS dest = wave-uniform base + lane*16
#define GLDS16(g, l)                                                        \
  __builtin_amdgcn_global_load_lds(                                        \
      (const __attribute__((address_space(1))) unsigned int*)(g),          \
      (__attribute__((address_space(3))) unsigned int*)(l), 16, 0, 0)

// ------------------------------------------------------------------
// fp32 -> bf16 convert, ALL 7 arrays in ONE launch (R18, verified).
// ------------------------------------------------------------------
__global__ __launch_bounds__(256) void cvt_all(const float* q, const float* k,
                                               const float* v, const float* wq,
                                               const float* wk, const float* wv,
                                               const float* wo, bf16_t* xq, bf16_t* xk,
                                               bf16_t* xv, bf16_t* wqkv, bf16_t* wob) {
  const size_t nIn = (size_t)MTOT * D_MODEL;   // 2^22
  const size_t nW = (size_t)D_MODEL * D_MODEL; // 2^20
  size_t e = ((size_t)blockIdx.x * 256 + threadIdx.x) * 8;
  const float* s;
  bf16_t* d;
  size_t off;
  if (e < 3 * nIn) {
    int j = (int)(e >> 22);
    off = e & (nIn - 1);
    s = j == 0 ? q : (j == 1 ? k : v);
    d = j == 0 ? xq : (j == 1 ? xk : xv);
  } else {
    size_t e2 = e - 3 * nIn;
    int j = (int)(e2 >> 20);
    off = e2 & (nW - 1);
    s = j == 0 ? wq : (j == 1 ? wk : (j == 2 ? wv : wo));
    d = j == 3 ? wob : (wqkv + (size_t)j * nW);
  }
  float4 a = *(const float4*)(s + off);
  float4 b = *(const float4*)(s + off + 4);
  bf16x8 o;
  o[0] = (bf16_t)a.x; o[1] = (bf16_t)a.y; o[2] = (bf16_t)a.z; o[3] = (bf16_t)a.w;
  o[4] = (bf16_t)b.x; o[5] = (bf16_t)b.y; o[6] = (bf16_t)b.z; o[7] = (bf16_t)b.w;
  *(bf16x8*)(d + off) = o;
}

// ------------------------------------------------------------------
// Fused QKV projection GEMM — R12-EXACT champion (63.4 us measured):
// 3-deep ring, counted vmcnt, raw s_barrier; per step i: vmcnt(4)
// [stage i landed; stage i+1 (4 ops) IN FLIGHT], raw s_barrier,
// issue stage(i+2) into buf (i+2)%3 (overwrites buf (i-1)%3 — finished
// by all waves before this barrier), then ds_read buf i%3 + MFMA.
// 128x128 tile, 512 thr / 8 waves (2Mx4N, per-wave 64x32), BK=64,
// LDS 3x32 KB = 96 KB. T2 XOR swizzle (pre-swizzled global source),
// XCD row-panel clustering. 768 blocks.
// Q out: [B,H,S,64] * QSCALE; K out: [B,H,S,64]; V out: [B,H,64,S].
// ------------------------------------------------------------------
__global__ __launch_bounds__(512, 2) void gemm_qkv(const bf16_t* __restrict__ Xq,
                                                   const bf16_t* __restrict__ Xk,
                                                   const bf16_t* __restrict__ Xv,
                                                   const bf16_t* __restrict__ Wqkv,
                                                   const float* __restrict__ bq,
                                                   const float* __restrict__ bk,
                                                   const float* __restrict__ bv,
                                                   bf16_t* __restrict__ qa,
                                                   bf16_t* __restrict__ ka,
                                                   bf16_t* __restrict__ vt) {
  __shared__ __align__(16) bf16_t As[3][128 * 64];  // 16 KB x3
  __shared__ __align__(16) bf16_t Bs[3][128 * 64];  // 16 KB x3
  const int t = threadIdx.x;
  const int f = blockIdx.x;
  const int xcd = f & 7, fi = f >> 3;  // fi 0..95
  const int by = xcd * 4 + (fi & 3);   // row-panel 0..31 (XCD-clustered)
  const int col = fi >> 2;             // col-panel 0..23
  const int seg = col >> 3;            // 0=Q 1=K 2=V
  const bf16_t* X = seg == 0 ? Xq : (seg == 1 ? Xk : Xv);
  const float* bias = seg == 0 ? bq : (seg == 1 ? bk : bv);
  const float scale = seg == 0 ? QSCALE : 1.0f;
  const int m0 = by * 128;
  const int n0g = col * 128;  // global col in [0,3072)
  const int w = t >> 6, l = t & 63, lr = l & 15, lg = l >> 4;
  const int wm = (w >> 2) * 64, wn = (w & 3) * 32;

  f32x4 acc[4][2] = {};

  // staging: chunk idx = p*512+t -> phys (row=idx>>3, c=idx&7);
  // source col chunk = c ^ (row&7)  (T2 pre-swizzled source)
  const int srow0 = t >> 3;
  const int sck = (((t & 7) ^ (srow0 & 7)) << 3);
  const int sx = (lr & 7) << 4;  // read-side XOR (row&7 == lr&7)

#define QKV_STAGE(buf, kt)                                                      \
  {                                                                             \
    _Pragma("unroll") for (int p = 0; p < 2; ++p) {                             \
      int row = (p * 512 + t) >> 3;                                             \
      int wb = (p * 512 + w * 64) * 8;                                          \
      GLDS16(&X[(size_t)(m0 + row) * D_MODEL + (kt) + sck], As[buf] + wb);      \
      GLDS16(&Wqkv[(size_t)(n0g + row) * D_MODEL + (kt) + sck], Bs[buf] + wb);  \
    }                                                                           \
  }

  QKV_STAGE(0, 0);
  QKV_STAGE(1, 64);

  int cur = 0;
  for (int step = 0; step < 16; ++step) {
    // stage(step) complete (its 4 DMA ops are the oldest); stage(step+1)
    // (4 ops) may remain in flight. Last step: everything must be done.
    if (step < 15)
      asm volatile("s_waitcnt vmcnt(4)" ::: "memory");
    else
      asm volatile("s_waitcnt vmcnt(0)" ::: "memory");
    __builtin_amdgcn_s_barrier();  // raw: no vmcnt(0) drain
    if (step + 2 < 16) {
      int nb = cur + 2; nb = nb >= 3 ? nb - 3 : nb;
      QKV_STAGE(nb, (step + 2) * 64);  // overwrites buf (step-1)%3: safe
    }
#pragma unroll
    for (int kk = 0; kk < 2; ++kk) {
      bf16x8 a[4], b[2];
#pragma unroll
      for (int i = 0; i < 4; ++i)
        a[i] = *(const bf16x8*)((const char*)As[cur] + (wm + i * 16 + lr) * 128 +
                                ((kk * 64 + lg * 16) ^ sx));
#pragma unroll
      for (int j = 0; j < 2; ++j)
        b[j] = *(const bf16x8*)((const char*)Bs[cur] + (wn + j * 16 + lr) * 128 +
                                ((kk * 64 + lg * 16) ^ sx));
      __builtin_amdgcn_s_setprio(1);
#pragma unroll
      for (int i = 0; i < 4; ++i)
#pragma unroll
        for (int j = 0; j < 2; ++j)
          acc[i][j] = __builtin_amdgcn_mfma_f32_16x16x32_bf16(a[i], b[j], acc[i][j], 0, 0, 0);
      __builtin_amdgcn_s_setprio(0);
    }
    cur = cur + 1 >= 3 ? 0 : cur + 1;
  }
#undef QKV_STAGE

  // epilogue: D layout col = lane&15, row = (lane>>4)*4 + reg  [m89-verified]
#pragma unroll
  for (int i = 0; i < 4; ++i) {
#pragma unroll
    for (int j = 0; j < 2; ++j) {
      int lc = ((n0g + wn) & 1023) + j * 16 + lr;  // segment-local col
      float bb = bias[lc];
      int h = lc >> 6, d = lc & 63;
#pragma unroll
      for (int ii = 0; ii < 4; ++ii) {
        int row = m0 + wm + i * 16 + lg * 4 + ii;
        float v = (acc[i][j][ii] + bb) * scale;
        int s = row >> 1, b2 = row & 1;
        if (seg == 2)
          vt[(((size_t)(b2 * HEADS + h) * D_K) + d) * SEQ + s] = (bf16_t)v;
        else if (seg == 1)
          ka[(((size_t)(b2 * HEADS + h) * SEQ) + s) * D_K + d] = (bf16_t)v;
        else
          qa[(((size_t)(b2 * HEADS + h) * SEQ) + s) * D_K + d] = (bf16_t)v;
      }
    }
  }
}

// ------------------------------------------------------------------
// Output GEMM: out[m][n] = ctx[m,:].Wo[n,:] + bo[n], fp32 out.
// 128x128 tile, 512 threads / 8 waves (2x4), 2-phase double-buffered,
// XCD row-panel clustering + T2 LDS swizzle.  (R12 version, verified)
// ------------------------------------------------------------------
__global__ __launch_bounds__(512) void gemm_out(const bf16_t* __restrict__ X,
                                                const bf16_t* __restrict__ W,
                                                const float* __restrict__ bias,
                                                float* __restrict__ out) {
  __shared__ __align__(16) bf16_t As[2][128 * 64];
  __shared__ __align__(16) bf16_t Bs[2][128 * 64];
  const int t = threadIdx.x;
  const int f = blockIdx.x;
  const int xcd = f & 7, fi = f >> 3;
  const int by = xcd * 4 + (fi & 3);
  const int bx = fi >> 2;  // 0..7
  const int m0 = by * 128, n0 = bx * 128;
  const int w = t >> 6, l = t & 63, lr = l & 15, lg = l >> 4;
  const int wm = (w >> 2) * 64, wn = (w & 3) * 32;
  const int srow0 = t >> 3;
  const int sck = (((t & 7) ^ (srow0 & 7)) << 3);
  const int sx = (lr & 7) << 4;

  f32x4 acc[4][2] = {};

#define OUT_STAGE(buf, kt)                                                      \
  {                                                                             \
    _Pragma("unroll") for (int p = 0; p < 2; ++p) {                             \
      int row = (p * 512 + t) >> 3;                                             \
      int wb = (p * 512 + w * 64) * 8;                                          \
      GLDS16(&X[(size_t)(m0 + row) * D_MODEL + (kt) + sck], As[buf] + wb);      \
      GLDS16(&W[(size_t)(n0 + row) * D_MODEL + (kt) + sck], Bs[buf] + wb);      \
    }                                                                           \
  }

  OUT_STAGE(0, 0);
  __syncthreads();

  for (int step = 0; step < 16; ++step) {
    const int cur = step & 1;
    if (step + 1 < 16) OUT_STAGE(cur ^ 1, (step + 1) * 64);
#pragma unroll
    for (int kk = 0; kk < 2; ++kk) {
      bf16x8 a[4], b[2];
#pragma unroll
      for (int i = 0; i < 4; ++i)
        a[i] = *(const bf16x8*)((const char*)As[cur] + (wm + i * 16 + lr) * 128 +
                                ((kk * 64 + lg * 16) ^ sx));
#pragma unroll
      for (int j = 0; j < 2; ++j)
        b[j] = *(const bf16x8*)((const char*)Bs[cur] + (wn + j * 16 + lr) * 128 +
                                ((kk * 64 + lg * 16) ^ sx));
#pragma unroll
      for (int i = 0; i < 4; ++i)
#pragma unroll
        for (int j = 0; j < 2; ++j)
          acc[i][j] = __builtin_amdgcn_mfma_f32_16x16x32_bf16(a[i], b[j], acc[i][j], 0, 0, 0);
    }
    __syncthreads();
  }
#undef OUT_STAGE

#pragma unroll
  for (int i = 0; i < 4; ++i) {
#pragma unroll
    for (int j = 0; j < 2; ++j) {
      int col = n0 + wn + j * 16 + lr;
      float bb = bias[col];
#pragma unroll
      for (int ii = 0; ii < 4; ++ii) {
        int row = m0 + wm + i * 16 + lg * 4 + ii;
        out[(size_t)row * D_MODEL + col] = acc[i][j][ii] + bb;
      }
    }
  }
}

// ------------------------------------------------------------------
// Flash attention, transposed-score form, LDS-staged K/V, NO-MAX softmax
// in the exp2 domain (log2e folded into Q scale and bias table).
// 512 threads = 8 waves, 128 q/block, K-tiles of 64, dbuf global_load_lds.
// (R12/R18 champion — verified 130.9/132.0; ring, dual-q, and LDS-diet
// variants all measured slower.)
// ------------------------------------------------------------------
#define QBLK 128
#define KVBLK 64
#define NT (SEQ / KVBLK)
#define TBL_N 2175
#define LDP 72

__global__ __launch_bounds__(512, 4) void attn_kernel(const bf16_t* __restrict__ Qa,
                                                      const bf16_t* __restrict__ Ka,
                                                      const bf16_t* __restrict__ Vt,
                                                      const float* __restrict__ rel,
                                                      bf16_t* __restrict__ ctx) {
  __shared__ float rbl[TBL_N + 1];                     // reversed, pre-scaled bias
  __shared__ __align__(16) bf16_t ks[2][KVBLK * 64];   // [k][d], chunk-swizzled
  __shared__ __align__(16) bf16_t vs[2][KVBLK * 64];   // [d][k], chunk-swizzled
  __shared__ __align__(16) bf16_t p_lds[8][16 * LDP];  // per-wave P [q16][k64]

  // bijective XCD swizzle: 512 blocks -> 64 consecutive per XCD (bh-major)
  const int f = blockIdx.x;
  const int nf = (f & 7) * 64 + (f >> 3);
  const int qb = nf & 15, bh = nf >> 4;
  const int h = bh & (HEADS - 1), b2 = bh >> 4;
  const int qbase = qb * QBLK;
  const int t = threadIdx.x, w = t >> 6, l = t & 63, lr = l & 15, lg = l >> 4;

  const bf16_t* Qbh = Qa + (size_t)bh * SEQ * D_K;
  const bf16_t* Kbh = Ka + (size_t)bh * SEQ * D_K;
  const bf16_t* Vbh = Vt + (size_t)bh * D_K * SEQ;

  // reversed bias table: rbl[j] = log2e * rel_head[qbase + 2174 - j]
  for (int j = t; j < TBL_N; j += 512)
    rbl[j] = LOG2E * rel[(size_t)(qbase + (TBL_N - 1) - j) * HEADS + h];

  // staging: thread t -> 16B chunk (row=t>>3, physchunk=t&7);
  // phys chunk holds source col16 = (t&7) ^ (row&7)  (read-side XOR matches)
  const int srow = t >> 3;
  const int scol = (((t & 7) ^ (srow & 7)) << 3);
  const int sldsoff = w * 512;

  const int qloc = w * 16 + lr;  // this lane's q (block-local)
  bf16x8 qf[2];
#pragma unroll
  for (int kk = 0; kk < 2; ++kk)
    qf[kk] = *(const bf16x8*)(&Qbh[(size_t)(qbase + qloc) * D_K + kk * 32 + lg * 8]);

  bf16x8 ones;
#pragma unroll
  for (int e = 0; e < 8; ++e) ones[e] = (bf16_t)1.0f;

  GLDS16(Kbh + (size_t)srow * D_K + scol, ks[0] + sldsoff);
  GLDS16(Vbh + (size_t)srow * SEQ + scol, vs[0] + sldsoff);
  __syncthreads();  // drains staging vmcnt + covers rbl

  f32x4 acc_o[4] = {};  // acc_o[c][ii] = O[d = c*16 + lg*4 + ii][q = qloc]
  f32x4 l_acc = {};     // all entries = running denominator for q = qloc
  bf16_t* pw = p_lds[w];
  const int sw = (lr & 7) << 4;          // read-side chunk XOR
  const int roff = 127 - qloc + lg * 4;  // reversed-table base offset

  for (int it = 0; it < NT; ++it) {
    const int cur = it & 1;
    const int kt = it * KVBLK;
    if (it + 1 < NT) {
      const int ktn = kt + KVBLK;
      GLDS16(Kbh + (size_t)(ktn + srow) * D_K + scol, ks[cur ^ 1] + sldsoff);
      GLDS16(Vbh + (size_t)srow * SEQ + ktn + scol, vs[cur ^ 1] + sldsoff);
    }
    const char* Kc = (const char*)ks[cur];
    const char* Vc = (const char*)vs[cur];

    // ---- S^T tile in exp2 domain, bias as C-init; P = exp2(z) ----
#pragma unroll
    for (int c = 0; c < 4; ++c) {
      const int r0 = roff + kt + c * 16;
      f32x4 z;
      z[0] = rbl[r0]; z[1] = rbl[r0 + 1]; z[2] = rbl[r0 + 2]; z[3] = rbl[r0 + 3];
#pragma unroll
      for (int kk = 0; kk < 2; ++kk) {
        bf16x8 kf = *(const bf16x8*)(Kc + (c * 16 + lr) * 128 + ((kk * 64 + lg * 16) ^ sw));
        z = __builtin_amdgcn_mfma_f32_16x16x32_bf16(kf, qf[kk], z, 0, 0, 0);
      }
      bf16x4 pv;
#pragma unroll
      for (int i = 0; i < 4; ++i) pv[i] = (bf16_t)__builtin_amdgcn_exp2f(z[i]);
      *(bf16x4*)(&pw[lr * LDP + c * 16 + lg * 4]) = pv;
    }

    // ---- PV: O^T += V^T_frag x P_frag ; l += ones x P_frag ----
    __builtin_amdgcn_s_setprio(1);
#pragma unroll
    for (int kk = 0; kk < 2; ++kk) {
      bf16x8 pa = *(const bf16x8*)(&pw[lr * LDP + kk * 32 + lg * 8]);
      l_acc = __builtin_amdgcn_mfma_f32_16x16x32_bf16(ones, pa, l_acc, 0, 0, 0);
#pragma unroll
      for (int c = 0; c < 4; ++c) {
        bf16x8 vf = *(const bf16x8*)(Vc + (c * 16 + lr) * 128 + ((kk * 64 + lg * 16) ^ sw));
        acc_o[c] = __builtin_amdgcn_mfma_f32_16x16x32_bf16(vf, pa, acc_o[c], 0, 0, 0);
      }
    }
    __builtin_amdgcn_s_setprio(0);
    __syncthreads();  // stage(it+1) landed; all waves done reading cur
  }

  const float inv = 1.0f / l_acc[0];

  int qg = qbase + qloc;
  size_t base = ((size_t)qg * BATCH + b2) * D_MODEL + h * D_K;
#pragma unroll
  for (int c = 0; c < 4; ++c) {
    bf16x4 ov;
#pragma unroll
    for (int ii = 0; ii < 4; ++ii) ov[ii] = (bf16_t)(acc_o[c][ii] * inv);
    *(bf16x4*)(&ctx[base + c * 16 + lg * 4]) = ov;
  }
}

// ------------------------------------------------------------------
extern "C" void kernel_launch(void* const* d_in, const int* in_sizes, int n_in,
                              void* d_out, int out_size, void* d_ws, size_t ws_size,
                              hipStream_t stream) {
  const float* query = (const float*)d_in[0];
  const float* key_i = (const float*)d_in[1];
  const float* value = (const float*)d_in[2];
  const float* Wq = (const float*)d_in[3];
  const float* bq = (const float*)d_in[4];
  const float* Wk = (const float*)d_in[5];
  const float* bk = (const float*)d_in[6];
  const float* Wv = (const float*)d_in[7];
  const float* bv = (const float*)d_in[8];
  const float* Wo = (const float*)d_in[9];
  const float* bo = (const float*)d_in[10];
  const float* rel = (const float*)d_in[11];
  float* out = (float*)d_out;

  char* ws = (char*)d_ws;
  size_t off = 0;
  auto alloc = [&](size_t bytes) {
    char* p = ws + off;
    off = (off + bytes + 255) & ~(size_t)255;
    return p;
  };
  const size_t nIn = (size_t)MTOT * D_MODEL;
  const size_t nW = (size_t)D_MODEL * D_MODEL;

  bf16_t* Xq = (bf16_t*)alloc(nIn * 2);
  bf16_t* Xk = (bf16_t*)alloc(nIn * 2);
  bf16_t* Xv = (bf16_t*)alloc(nIn * 2);
  bf16_t* Wqkv = (bf16_t*)alloc(3 * nW * 2);  // Wq | Wk | Wv rows, contiguous
  bf16_t* Wob = (bf16_t*)alloc(nW * 2);
  bf16_t* qa = (bf16_t*)alloc(nIn * 2);   // [B,H,S,64]
  bf16_t* ka = (bf16_t*)alloc(nIn * 2);   // [B,H,S,64]
  bf16_t* vt = (bf16_t*)alloc(nIn * 2);   // [B,H,64,S]
  bf16_t* ctx = (bf16_t*)alloc(nIn * 2);  // [M,1024]

  // one fused cvt launch: (3*nIn + 4*nW)/8 threads = 8192 blocks
  cvt_all<<<dim3(8192), 256, 0, stream>>>(query, key_i, value, Wq, Wk, Wv, Wo, Xq, Xk,
                                          Xv, Wqkv, Wob);

  gemm_qkv<<<dim3(768), 512, 0, stream>>>(Xq, Xk, Xv, Wqkv, bq, bk, bv, qa, ka, vt);

  attn_kernel<<<dim3(512), 512, 0, stream>>>(qa, ka, vt, rel, ctx);

  gemm_out<<<dim3(256), 512, 0, stream>>>(ctx, Wob, bo, out);
}